// Round 2
// baseline (239.148 us; speedup 1.0000x reference)
//
#include <hip/hip_runtime.h>
#include <hip/hip_bf16.h>

// out[b,j] = sum_{i,k} coef[j,i,k] * tanh(x[b,i])^k
// B=8192, IN=1024, OUT=1024, ORDER=7.
// k=0 plane -> per-j bias (computed in prep, added in gemm epilogue).
// GEMM: M=8192, N=1024, K=IN*7=7168, bf16 MFMA.
//
// Round 10:
//  * K reordered to PLANE-MAJOR: K-index = (k-1)*1024 + i  (7 planes of 1024).
//    prep now needs NO LDS transpose: each thread's 7 output chunks (one per
//    power-plane) are 16B/lane fully coalesced stores. No syncthreads, no
//    div/mod shuffle math. GEMM is layout-oblivious (A and coef_bf match).
//  * gemm_bt back to the round-8 skeleton (128x128 tile, 4 waves, 64x64/wave,
//    2 blocks/CU, ONE __syncthreads per K-tile) but BK=64 + double-buffered
//    LDS with next-tile global_load_lds issued at loop TOP, so loads overlap
//    this tile's ds_read+MFMA window instead of being drained cold.
//    (Round-9 post-mortem: 4x barrier rate + 1 lockstep block/CU regressed;
//    LDS-read pipe caps MfmaUtil at ~60% for 64x64 wave tiles.)
//  * XOR swizzle kept: LDS slot s (16B chunks, 8/row) of row r holds global
//    chunk s^(r&7); linear LDS dest + pre-swizzled global source. 0 conflicts
//    measured in round 9.

#define KT 7168
#define KFULL 8192

#define TM 128
#define TN 128
#define TK 64
#define NT (KT / TK)   // 112

// fallback tile
#define BM 128
#define BN 128

typedef short bf16x8 __attribute__((ext_vector_type(8)));
typedef short bf16x4 __attribute__((ext_vector_type(4)));
typedef float f32x4  __attribute__((ext_vector_type(4)));

__device__ __forceinline__ unsigned short f2bf(float f) {
    union { float f; unsigned u; } v; v.f = f;
    unsigned r = v.u + 0x7fffu + ((v.u >> 16) & 1u);   // RTE
    return (unsigned short)(r >> 16);
}

__device__ __forceinline__ void gload_lds16(const void* gp, void* lp) {
    __builtin_amdgcn_global_load_lds(
        (const __attribute__((address_space(1))) void*)gp,
        (__attribute__((address_space(3))) void*)lp, 16, 0, 0);
}

// ---- pass 1: prep (plane-major, LDS-free) ----
#define CVT_BLOCKS  512
#define TANH_BLOCKS 4096

__global__ __launch_bounds__(256)
void prep(const float* __restrict__ x, const float* __restrict__ trp,
          const float* __restrict__ coef, unsigned short* __restrict__ coef_bf,
          unsigned short* __restrict__ A, float* __restrict__ bias) {
    __shared__ float redbuf[4];

    const int t   = threadIdx.x;
    const int blk = blockIdx.x;
    const int rl  = t >> 7;        // row_local 0/1
    const int ig  = t & 127;       // i-group (8 i's each)

    if (blk < CVT_BLOCKS) {
        // ---- coef conversion: row j, k=1..7 -> planes 0..6; k=0 -> bias ----
        const int j = blk * 2 + rl;
        const float* src = coef + (size_t)j * KFULL + ig * 64;
        float k0sum = 0.f;
        bf16x8 pl[7];
        #pragma unroll
        for (int i = 0; i < 8; ++i) {
            const float4 f0 = *(const float4*)(src + i * 8);
            const float4 f1 = *(const float4*)(src + i * 8 + 4);
            k0sum += f0.x;
            pl[0][i] = (short)f2bf(f0.y); pl[1][i] = (short)f2bf(f0.z);
            pl[2][i] = (short)f2bf(f0.w); pl[3][i] = (short)f2bf(f1.x);
            pl[4][i] = (short)f2bf(f1.y); pl[5][i] = (short)f2bf(f1.z);
            pl[6][i] = (short)f2bf(f1.w);
        }
        #pragma unroll
        for (int off = 32; off > 0; off >>= 1) k0sum += __shfl_down(k0sum, off, 64);
        if ((t & 63) == 0) redbuf[t >> 6] = k0sum;
        __syncthreads();
        if (t == 0)   bias[j]     = redbuf[0] + redbuf[1];
        if (t == 128) bias[j]     = redbuf[2] + redbuf[3];

        unsigned short* dst = coef_bf + (size_t)j * KT + ig * 8;
        #pragma unroll
        for (int p = 0; p < 7; ++p)
            *(bf16x8*)(dst + p * 1024) = pl[p];   // coalesced: 16B/lane contiguous
    } else {
        // ---- tanh powers: row bb, plane p holds tanh(x)^(p+1) ----
        const int bb = (blk - CVT_BLOCKS) * 2 + rl;
        const float tr = trp[0];
        const float* xp = x + (size_t)bb * 1024 + ig * 8;
        const float4 x0 = *(const float4*)xp;
        const float4 x1 = *(const float4*)(xp + 4);
        const float xs[8] = {x0.x, x0.y, x0.z, x0.w, x1.x, x1.y, x1.z, x1.w};
        bf16x8 pl[7];
        #pragma unroll
        for (int i = 0; i < 8; ++i) {
            const float e  = __expf(2.0f * tr * xs[i]);
            const float tt = 1.0f - 2.0f * __builtin_amdgcn_rcpf(e + 1.0f);  // tanh(tr*x)
            float pw = tt;
            #pragma unroll
            for (int p = 0; p < 7; ++p) { pl[p][i] = (short)f2bf(pw); pw *= tt; }
        }
        unsigned short* dst = A + (size_t)bb * KT + ig * 8;
        #pragma unroll
        for (int p = 0; p < 7; ++p)
            *(bf16x8*)(dst + p * 1024) = pl[p];   // coalesced: 16B/lane contiguous
    }
}

// ---- pass 2: NT GEMM (K=7168), 128x128 tile, BK=64, dbuf + early prefetch ----
__global__ __launch_bounds__(256, 2)
void gemm_bt(const unsigned short* __restrict__ A, const unsigned short* __restrict__ Bt,
             const float* __restrict__ bias, float* __restrict__ out)
{
    __shared__ unsigned short As[2][TM * TK];   // 2 x 16 KB
    __shared__ unsigned short Bs[2][TN * TK];   // 2 x 16 KB  -> 64 KB total, 2 blocks/CU

    const int t    = threadIdx.x;
    const int m0   = blockIdx.x * TM;   // x = m-tile: A-sharers (same x, all y) land on same XCD
    const int n0   = blockIdx.y * TN;
    const int w    = t >> 6;
    const int lane = t & 63;
    const int wm   = (w >> 1) * 64;
    const int wn   = (w & 1) * 64;
    const int lrow = lane & 15;
    const int lq   = lane >> 4;

    // fragment-read swizzle: chunk c=(kk>>3)+lq lives at slot c^(row&7);
    // row&7 == lane&7 for all fragment rows.
    const int S = ((lq ^ (lane & 7)) << 3);   // ushort offset of kk=0 slot

    // staging: thread t covers row (srow + r*32), LDS slot (t&7) -> global
    // chunk (t&7)^(srow&7).  gload dest is wave-uniform base + lane*16.
    const int srow = t >> 3;                  // 0..31
    const int schk = (t & 7) ^ (srow & 7);
    const size_t aG = (size_t)(m0 + srow) * KT + schk * 8;
    const size_t bG = (size_t)(n0 + srow) * KT + schk * 8;
    const int wofs = w * 512;                 // ushorts

    f32x4 acc[4][4];
    #pragma unroll
    for (int i = 0; i < 4; i++)
        #pragma unroll
        for (int j = 0; j < 4; j++)
            acc[i][j] = (f32x4){0.f, 0.f, 0.f, 0.f};

    // prologue: stage tile 0 into buf 0
    #pragma unroll
    for (int r = 0; r < 4; ++r) {
        gload_lds16(A  + aG + (size_t)(r * 32) * KT, &As[0][r * 2048 + wofs]);
        gload_lds16(Bt + bG + (size_t)(r * 32) * KT, &Bs[0][r * 2048 + wofs]);
    }
    __syncthreads();   // drains vmcnt -> tile 0 resident

    for (int kt = 0; kt < NT; ++kt) {
        const int cur = kt & 1;

        // issue next tile's loads FIRST: they fly during ds_read + MFMA below
        if (kt + 1 < NT) {
            const size_t ko = (size_t)(kt + 1) * TK;
            #pragma unroll
            for (int r = 0; r < 4; ++r) {
                gload_lds16(A  + aG + (size_t)(r * 32) * KT + ko, &As[cur ^ 1][r * 2048 + wofs]);
                gload_lds16(Bt + bG + (size_t)(r * 32) * KT + ko, &Bs[cur ^ 1][r * 2048 + wofs]);
            }
        }

        const unsigned short* as = As[cur];
        const unsigned short* bs = Bs[cur];
        bf16x8 a[2][4], b[2][4];
        #pragma unroll
        for (int i = 0; i < 4; ++i) {
            const int ro = (wm + i * 16 + lrow) * TK + S;
            a[0][i] = *(const bf16x8*)&as[ro];
            a[1][i] = *(const bf16x8*)&as[ro ^ 32];   // kk=32: slot^4
        }
        #pragma unroll
        for (int j = 0; j < 4; ++j) {
            const int ro = (wn + j * 16 + lrow) * TK + S;
            b[0][j] = *(const bf16x8*)&bs[ro];
            b[1][j] = *(const bf16x8*)&bs[ro ^ 32];
        }
        #pragma unroll
        for (int kk = 0; kk < 2; ++kk)
            #pragma unroll
            for (int i = 0; i < 4; ++i)
                #pragma unroll
                for (int j = 0; j < 4; ++j)
                    acc[i][j] = __builtin_amdgcn_mfma_f32_16x16x32_bf16(
                        a[kk][i], b[kk][j], acc[i][j], 0, 0, 0);

        // one sync per tile: drains this iter's prefetch (vmcnt) + makes
        // buf cur reusable for writing next iter (all waves done reading).
        __syncthreads();
    }

    const int crow = (lane >> 4) * 4;
    const int ccol = lane & 15;
    #pragma unroll
    for (int j = 0; j < 4; j++) {
        const int n = n0 + wn + j * 16 + ccol;
        const float bv = bias[n];
        #pragma unroll
        for (int i = 0; i < 4; i++) {
            const int m = m0 + wm + i * 16 + crow;
            #pragma unroll
            for (int r = 0; r < 4; ++r)
                out[(size_t)(m + r) * 1024 + n] = acc[i][j][r] + bv;
        }
    }
}

// ---- fallback: fused kernel (full K=8192), used only if ws too small ----
#define LDK 72
__global__ __launch_bounds__(256, 2)
void taylor_gemm(const float* __restrict__ x, const float* __restrict__ trp,
                 const float* __restrict__ coef, float* __restrict__ out)
{
    __shared__ unsigned short As[BM * LDK];
    __shared__ unsigned short Bs[BN * LDK];

    const int t  = threadIdx.x;
    const int m0 = blockIdx.x * BM;
    const int n0 = blockIdx.y * BN;
    const float tr = trp[0];

    const int w    = t >> 6;
    const int lane = t & 63;
    const int wm   = (w >> 1) * 64;
    const int wn   = (w & 1) * 64;
    const int lrow = lane & 15;
    const int kq   = (lane >> 4) * 8;

    f32x4 acc[4][4];
    #pragma unroll
    for (int i = 0; i < 4; i++)
        #pragma unroll
        for (int j = 0; j < 4; j++)
            acc[i][j] = (f32x4){0.f, 0.f, 0.f, 0.f};

    const int bcol  = t & 15;
    const int brow0 = t >> 4;
    const int acol  = t & 7;
    const int arow0 = t >> 3;

    for (int k0 = 0; k0 < KFULL; k0 += 64) {
        const int i0 = k0 >> 3;
        #pragma unroll
        for (int r = 0; r < 8; ++r) {
            const int row = brow0 + r * 16;
            const float4 v = *(const float4*)(coef + (size_t)(n0 + row) * KFULL + k0 + bcol * 4);
            bf16x4 pk;
            pk[0] = (short)f2bf(v.x); pk[1] = (short)f2bf(v.y);
            pk[2] = (short)f2bf(v.z); pk[3] = (short)f2bf(v.w);
            *(bf16x4*)&Bs[row * LDK + bcol * 4] = pk;
        }
        #pragma unroll
        for (int r = 0; r < 4; ++r) {
            const int row = arow0 + r * 32;
            const float xv = x[(size_t)(m0 + row) * 1024 + i0 + acol];
            const float e  = __expf(2.0f * tr * xv);
            const float tt = 1.0f - 2.0f / (e + 1.0f);
            bf16x8 pk;
            float p = 1.0f;
            #pragma unroll
            for (int k = 0; k < 8; ++k) { pk[k] = (short)f2bf(p); p *= tt; }
            *(bf16x8*)&As[row * LDK + acol * 8] = pk;
        }
        __syncthreads();
        #pragma unroll
        for (int kk = 0; kk < 64; kk += 32) {
            bf16x8 a[4], b[4];
            #pragma unroll
            for (int i = 0; i < 4; i++)
                a[i] = *(const bf16x8*)&As[(wm + i * 16 + lrow) * LDK + kk + kq];
            #pragma unroll
            for (int j = 0; j < 4; j++)
                b[j] = *(const bf16x8*)&Bs[(wn + j * 16 + lrow) * LDK + kk + kq];
            #pragma unroll
            for (int i = 0; i < 4; i++)
                #pragma unroll
                for (int j = 0; j < 4; j++)
                    acc[i][j] = __builtin_amdgcn_mfma_f32_16x16x32_bf16(a[i], b[j], acc[i][j], 0, 0, 0);
        }
        __syncthreads();
    }

    const int crow = (lane >> 4) * 4;
    const int ccol = lane & 15;
    #pragma unroll
    for (int i = 0; i < 4; i++) {
        #pragma unroll
        for (int j = 0; j < 4; j++) {
            const int m = m0 + wm + i * 16 + crow;
            const int n = n0 + wn + j * 16 + ccol;
            #pragma unroll
            for (int r = 0; r < 4; ++r)
                out[(size_t)(m + r) * 1024 + n] = acc[i][j][r];
        }
    }
}

extern "C" void kernel_launch(void* const* d_in, const int* in_sizes, int n_in,
                              void* d_out, int out_size, void* d_ws, size_t ws_size,
                              hipStream_t stream) {
    const float* x    = (const float*)d_in[0];
    const float* trp  = (const float*)d_in[1];
    const float* coef = (const float*)d_in[2];
    float* out = (float*)d_out;

    const size_t A_BYTES    = (size_t)8192 * KT * 2;   // 117,440,512
    const size_t COEF_BYTES = (size_t)1024 * KT * 2;   //  14,680,064
    const size_t BIAS_BYTES = 1024 * sizeof(float);

    if (ws_size >= A_BYTES + COEF_BYTES + BIAS_BYTES) {
        unsigned short* A_bf    = (unsigned short*)d_ws;
        unsigned short* coef_bf = (unsigned short*)((char*)d_ws + A_BYTES);
        float*          bias    = (float*)((char*)d_ws + A_BYTES + COEF_BYTES);

        prep<<<dim3(CVT_BLOCKS + TANH_BLOCKS), dim3(256), 0, stream>>>(
            x, trp, coef, coef_bf, A_bf, bias);
        gemm_bt<<<dim3(8192 / TM, 1024 / TN), dim3(256), 0, stream>>>(
            A_bf, coef_bf, bias, out);
    } else {
        taylor_gemm<<<dim3(8192 / BM, 1024 / BN), dim3(256), 0, stream>>>(x, trp, coef, out);
    }
}

// Round 3
// 229.632 us; speedup vs baseline: 1.0414x; 1.0414x over previous
//
#include <hip/hip_runtime.h>
#include <hip/hip_bf16.h>

// out[b,j] = sum_{i,k} coef[j,i,k] * tanh(x[b,i])^k
// B=8192, IN=1024, OUT=1024, ORDER=7.
// k=0 plane -> per-j bias (computed in prep, added in gemm epilogue).
// GEMM: M=8192, N=1024, K=IN*7=7168, bf16 MFMA.
//
// Round 11:
//  * gemm_bt reverted VERBATIM to round-8 (119 us, MfmaUtil 45%): BK=128
//    single-buffer cold-stage, 2 blocks/CU anti-phased, 1 barrier per 64-K.
//    Round-9 (8-phase port) and round-10 (BK=64 dbuf prefetch) both regressed:
//    source-level pipelining loses to the anti-phased cold-stage here.
//  * prep stays plane-major (K-index = (k-1)*1024 + i, LDS-free, coalesced
//    16B/lane stores) but f2bf now uses __float2bfloat16 so the compiler can
//    emit v_cvt_pk_bf16_f32 (m240: compiler cast codegen >= hand bit-hack).
//  * Residual analysis: total-gemm was 110/103/106 us across 3 different prep
//    versions -> residual is largely fixed harness cost; prep ~40-50 us.

#define KT 7168
#define KFULL 8192

// gemm tile (round-8)
#define BM 128
#define BN 128
#define BK 128

typedef short bf16x8 __attribute__((ext_vector_type(8)));
typedef short bf16x4 __attribute__((ext_vector_type(4)));
typedef float f32x4  __attribute__((ext_vector_type(4)));

__device__ __forceinline__ unsigned short f2bf(float f) {
    union { __hip_bfloat16 h; unsigned short u; } v;
    v.h = __float2bfloat16(f);   // RTE; compiler may fuse pairs into v_cvt_pk_bf16_f32
    return v.u;
}

__device__ __forceinline__ void gload_lds16(const void* gp, void* lp) {
    __builtin_amdgcn_global_load_lds(
        (const __attribute__((address_space(1))) void*)gp,
        (__attribute__((address_space(3))) void*)lp, 16, 0, 0);
}

// ---- pass 1: prep (plane-major, LDS-free) ----
#define CVT_BLOCKS  512
#define TANH_BLOCKS 4096

__global__ __launch_bounds__(256)
void prep(const float* __restrict__ x, const float* __restrict__ trp,
          const float* __restrict__ coef, unsigned short* __restrict__ coef_bf,
          unsigned short* __restrict__ A, float* __restrict__ bias) {
    __shared__ float redbuf[4];

    const int t   = threadIdx.x;
    const int blk = blockIdx.x;
    const int rl  = t >> 7;        // row_local 0/1
    const int ig  = t & 127;       // i-group (8 i's each)

    if (blk < CVT_BLOCKS) {
        // ---- coef conversion: row j, k=1..7 -> planes 0..6; k=0 -> bias ----
        const int j = blk * 2 + rl;
        const float* src = coef + (size_t)j * KFULL + ig * 64;
        float k0sum = 0.f;
        bf16x8 pl[7];
        #pragma unroll
        for (int i = 0; i < 8; ++i) {
            const float4 f0 = *(const float4*)(src + i * 8);
            const float4 f1 = *(const float4*)(src + i * 8 + 4);
            k0sum += f0.x;
            pl[0][i] = (short)f2bf(f0.y); pl[1][i] = (short)f2bf(f0.z);
            pl[2][i] = (short)f2bf(f0.w); pl[3][i] = (short)f2bf(f1.x);
            pl[4][i] = (short)f2bf(f1.y); pl[5][i] = (short)f2bf(f1.z);
            pl[6][i] = (short)f2bf(f1.w);
        }
        #pragma unroll
        for (int off = 32; off > 0; off >>= 1) k0sum += __shfl_down(k0sum, off, 64);
        if ((t & 63) == 0) redbuf[t >> 6] = k0sum;
        __syncthreads();
        if (t == 0)   bias[j] = redbuf[0] + redbuf[1];
        if (t == 128) bias[j] = redbuf[2] + redbuf[3];

        unsigned short* dst = coef_bf + (size_t)j * KT + ig * 8;
        #pragma unroll
        for (int p = 0; p < 7; ++p)
            *(bf16x8*)(dst + p * 1024) = pl[p];   // coalesced: 16B/lane contiguous
    } else {
        // ---- tanh powers: row bb, plane p holds tanh(x)^(p+1) ----
        const int bb = (blk - CVT_BLOCKS) * 2 + rl;
        const float tr = trp[0];
        const float* xp = x + (size_t)bb * 1024 + ig * 8;
        const float4 x0 = *(const float4*)xp;
        const float4 x1 = *(const float4*)(xp + 4);
        const float xs[8] = {x0.x, x0.y, x0.z, x0.w, x1.x, x1.y, x1.z, x1.w};
        bf16x8 pl[7];
        #pragma unroll
        for (int i = 0; i < 8; ++i) {
            const float e  = __expf(2.0f * tr * xs[i]);
            const float tt = 1.0f - 2.0f * __builtin_amdgcn_rcpf(e + 1.0f);  // tanh(tr*x)
            float pw = tt;
            #pragma unroll
            for (int p = 0; p < 7; ++p) { pl[p][i] = (short)f2bf(pw); pw *= tt; }
        }
        unsigned short* dst = A + (size_t)bb * KT + ig * 8;
        #pragma unroll
        for (int p = 0; p < 7; ++p)
            *(bf16x8*)(dst + p * 1024) = pl[p];   // coalesced: 16B/lane contiguous
    }
}

// ---- pass 2: NT GEMM (K=7168), round-8 structure: BK=128, cold-stage ----
// XOR swizzle (16 chunks/row): slot s of row m holds global chunk s^(m&15).
__global__ __launch_bounds__(256, 2)
void gemm_bt(const unsigned short* __restrict__ A, const unsigned short* __restrict__ Bt,
             const float* __restrict__ bias, float* __restrict__ out)
{
    __shared__ unsigned short As[BM * BK];   // 32 KB
    __shared__ unsigned short Bs[BN * BK];   // 32 KB

    const int t    = threadIdx.x;
    const int m0   = blockIdx.x * BM;   // x = m-tile: A-sharers land on same XCD
    const int n0   = blockIdx.y * BN;
    const int w    = t >> 6;
    const int lane = t & 63;
    const int wm   = (w >> 1) * 64;
    const int wn   = (w & 1) * 64;
    const int lrow = lane & 15;

    // staging: thread t covers row srow + r*16 (r=0..7); fetches swizzled
    // chunk schunk = (t&15)^srow so LDS slot s of row m holds chunk s^(m&15).
    const int srow   = t >> 4;           // 0..15
    const int schunk = (t & 15) ^ srow;
    const int wbase  = w * 512;          // ushort units; +lane*8 applied by HW

    f32x4 acc[4][4];
    #pragma unroll
    for (int i = 0; i < 4; i++)
        #pragma unroll
        for (int j = 0; j < 4; j++)
            acc[i][j] = (f32x4){0.f, 0.f, 0.f, 0.f};

    const size_t abase = (size_t)(m0 + srow) * KT + schunk * 8;
    const size_t bbase = (size_t)(n0 + srow) * KT + schunk * 8;

    for (int k0 = 0; k0 < KT; k0 += BK) {
        #pragma unroll
        for (int r = 0; r < 8; ++r)
            gload_lds16(A + abase + (size_t)r * 16 * KT + k0, &As[r * 2048 + wbase]);
        #pragma unroll
        for (int r = 0; r < 8; ++r)
            gload_lds16(Bt + bbase + (size_t)r * 16 * KT + k0, &Bs[r * 2048 + wbase]);

        __syncthreads();

        #pragma unroll
        for (int kk = 0; kk < BK; kk += 32) {
            // global chunk c = kk/8 + quad; stored at slot c^(m&15), m&15 == lane&15
            const int soff = ((((kk >> 3) + (lane >> 4)) ^ (lane & 15)) * 8);
            bf16x8 a[4], b[4];
            #pragma unroll
            for (int i = 0; i < 4; i++)
                a[i] = *(const bf16x8*)&As[(wm + i * 16 + lrow) * BK + soff];
            #pragma unroll
            for (int j = 0; j < 4; j++)
                b[j] = *(const bf16x8*)&Bs[(wn + j * 16 + lrow) * BK + soff];
            #pragma unroll
            for (int i = 0; i < 4; i++)
                #pragma unroll
                for (int j = 0; j < 4; j++)
                    acc[i][j] = __builtin_amdgcn_mfma_f32_16x16x32_bf16(a[i], b[j], acc[i][j], 0, 0, 0);
        }

        __syncthreads();
    }

    const int crow = (lane >> 4) * 4;
    const int ccol = lane & 15;
    #pragma unroll
    for (int j = 0; j < 4; j++) {
        const int n = n0 + wn + j * 16 + ccol;
        const float bv = bias[n];
        #pragma unroll
        for (int i = 0; i < 4; i++) {
            const int m = m0 + wm + i * 16 + crow;
            #pragma unroll
            for (int r = 0; r < 4; ++r)
                out[(size_t)(m + r) * 1024 + n] = acc[i][j][r] + bv;
        }
    }
}

// ---- fallback: fused kernel (full K=8192), used only if ws too small ----
#define LDK 72
__global__ __launch_bounds__(256, 2)
void taylor_gemm(const float* __restrict__ x, const float* __restrict__ trp,
                 const float* __restrict__ coef, float* __restrict__ out)
{
    __shared__ unsigned short As[BM * LDK];
    __shared__ unsigned short Bs[BN * LDK];

    const int t  = threadIdx.x;
    const int m0 = blockIdx.x * BM;
    const int n0 = blockIdx.y * BN;
    const float tr = trp[0];

    const int w    = t >> 6;
    const int lane = t & 63;
    const int wm   = (w >> 1) * 64;
    const int wn   = (w & 1) * 64;
    const int lrow = lane & 15;
    const int kq   = (lane >> 4) * 8;

    f32x4 acc[4][4];
    #pragma unroll
    for (int i = 0; i < 4; i++)
        #pragma unroll
        for (int j = 0; j < 4; j++)
            acc[i][j] = (f32x4){0.f, 0.f, 0.f, 0.f};

    const int bcol  = t & 15;
    const int brow0 = t >> 4;
    const int acol  = t & 7;
    const int arow0 = t >> 3;

    for (int k0 = 0; k0 < KFULL; k0 += 64) {
        const int i0 = k0 >> 3;
        #pragma unroll
        for (int r = 0; r < 8; ++r) {
            const int row = brow0 + r * 16;
            const float4 v = *(const float4*)(coef + (size_t)(n0 + row) * KFULL + k0 + bcol * 4);
            bf16x4 pk;
            pk[0] = (short)f2bf(v.x); pk[1] = (short)f2bf(v.y);
            pk[2] = (short)f2bf(v.z); pk[3] = (short)f2bf(v.w);
            *(bf16x4*)&Bs[row * LDK + bcol * 4] = pk;
        }
        #pragma unroll
        for (int r = 0; r < 4; ++r) {
            const int row = arow0 + r * 32;
            const float xv = x[(size_t)(m0 + row) * 1024 + i0 + acol];
            const float e  = __expf(2.0f * tr * xv);
            const float tt = 1.0f - 2.0f / (e + 1.0f);
            bf16x8 pk;
            float p = 1.0f;
            #pragma unroll
            for (int k = 0; k < 8; ++k) { pk[k] = (short)f2bf(p); p *= tt; }
            *(bf16x8*)&As[row * LDK + acol * 8] = pk;
        }
        __syncthreads();
        #pragma unroll
        for (int kk = 0; kk < 64; kk += 32) {
            bf16x8 a[4], b[4];
            #pragma unroll
            for (int i = 0; i < 4; i++)
                a[i] = *(const bf16x8*)&As[(wm + i * 16 + lrow) * LDK + kk + kq];
            #pragma unroll
            for (int j = 0; j < 4; j++)
                b[j] = *(const bf16x8*)&Bs[(wn + j * 16 + lrow) * LDK + kk + kq];
            #pragma unroll
            for (int i = 0; i < 4; i++)
                #pragma unroll
                for (int j = 0; j < 4; j++)
                    acc[i][j] = __builtin_amdgcn_mfma_f32_16x16x32_bf16(a[i], b[j], acc[i][j], 0, 0, 0);
        }
        __syncthreads();
    }

    const int crow = (lane >> 4) * 4;
    const int ccol = lane & 15;
    #pragma unroll
    for (int i = 0; i < 4; i++) {
        #pragma unroll
        for (int j = 0; j < 4; j++) {
            const int m = m0 + wm + i * 16 + crow;
            const int n = n0 + wn + j * 16 + ccol;
            #pragma unroll
            for (int r = 0; r < 4; ++r)
                out[(size_t)(m + r) * 1024 + n] = acc[i][j][r];
        }
    }
}

extern "C" void kernel_launch(void* const* d_in, const int* in_sizes, int n_in,
                              void* d_out, int out_size, void* d_ws, size_t ws_size,
                              hipStream_t stream) {
    const float* x    = (const float*)d_in[0];
    const float* trp  = (const float*)d_in[1];
    const float* coef = (const float*)d_in[2];
    float* out = (float*)d_out;

    const size_t A_BYTES    = (size_t)8192 * KT * 2;   // 117,440,512
    const size_t COEF_BYTES = (size_t)1024 * KT * 2;   //  14,680,064
    const size_t BIAS_BYTES = 1024 * sizeof(float);

    if (ws_size >= A_BYTES + COEF_BYTES + BIAS_BYTES) {
        unsigned short* A_bf    = (unsigned short*)d_ws;
        unsigned short* coef_bf = (unsigned short*)((char*)d_ws + A_BYTES);
        float*          bias    = (float*)((char*)d_ws + A_BYTES + COEF_BYTES);

        prep<<<dim3(CVT_BLOCKS + TANH_BLOCKS), dim3(256), 0, stream>>>(
            x, trp, coef, coef_bf, A_bf, bias);
        gemm_bt<<<dim3(8192 / BM, 1024 / BN), dim3(256), 0, stream>>>(
            A_bf, coef_bf, bias, out);
    } else {
        taylor_gemm<<<dim3(8192 / BM, 1024 / BN), dim3(256), 0, stream>>>(x, trp, coef, out);
    }
}